// Round 11
// baseline (83.654 us; speedup 1.0000x reference)
//
#include <hip/hip_runtime.h>
#include <math.h>

#define B 512
#define DG 1024
#define P 1024
#define DA 256
#define LDP 68
#define BP (B * P)
#define BD (B * DA)

// ---------------------------------------------------------------- reductions
__device__ __forceinline__ float block_reduce_sum(float v, volatile float* red) {
    #pragma unroll
    for (int off = 32; off > 0; off >>= 1) v += __shfl_down(v, off, 64);
    const int lane = threadIdx.x & 63, wid = threadIdx.x >> 6;
    __syncthreads();
    if (lane == 0) red[wid] = v;
    __syncthreads();
    return red[0] + red[1] + red[2] + red[3];
}
__device__ __forceinline__ float wsum(float v) {
    #pragma unroll
    for (int m = 32; m > 0; m >>= 1) v += __shfl_xor(v, m, 64);
    return v;
}
__device__ __forceinline__ float txsum(float v) {
    #pragma unroll
    for (int m = 8; m > 0; m >>= 1) v += __shfl_xor(v, m, 16);
    return v;
}

#define FMA16(a4, b4, acc)                                   \
    acc[0][0] = fmaf(a4.x, b4.x, acc[0][0]);                 \
    acc[0][1] = fmaf(a4.x, b4.y, acc[0][1]);                 \
    acc[0][2] = fmaf(a4.x, b4.z, acc[0][2]);                 \
    acc[0][3] = fmaf(a4.x, b4.w, acc[0][3]);                 \
    acc[1][0] = fmaf(a4.y, b4.x, acc[1][0]);                 \
    acc[1][1] = fmaf(a4.y, b4.y, acc[1][1]);                 \
    acc[1][2] = fmaf(a4.y, b4.z, acc[1][2]);                 \
    acc[1][3] = fmaf(a4.y, b4.w, acc[1][3]);                 \
    acc[2][0] = fmaf(a4.z, b4.x, acc[2][0]);                 \
    acc[2][1] = fmaf(a4.z, b4.y, acc[2][1]);                 \
    acc[2][2] = fmaf(a4.z, b4.z, acc[2][2]);                 \
    acc[2][3] = fmaf(a4.z, b4.w, acc[2][3]);                 \
    acc[3][0] = fmaf(a4.w, b4.x, acc[3][0]);                 \
    acc[3][1] = fmaf(a4.w, b4.y, acc[3][1]);                 \
    acc[3][2] = fmaf(a4.w, b4.z, acc[3][2]);                 \
    acc[3][3] = fmaf(a4.w, b4.w, acc[3][3]);

#define FMA8(a0, a1, b4, acc)                                \
    acc[0][0] = fmaf(a0, b4.x, acc[0][0]);                   \
    acc[0][1] = fmaf(a0, b4.y, acc[0][1]);                   \
    acc[0][2] = fmaf(a0, b4.z, acc[0][2]);                   \
    acc[0][3] = fmaf(a0, b4.w, acc[0][3]);                   \
    acc[1][0] = fmaf(a1, b4.x, acc[1][0]);                   \
    acc[1][1] = fmaf(a1, b4.y, acc[1][1]);                   \
    acc[1][2] = fmaf(a1, b4.z, acc[1][2]);                   \
    acc[1][3] = fmaf(a1, b4.w, acc[1][3]);

// ---------------------------------------------------------------- staging helpers
__device__ __forceinline__ void stage_T(const float* __restrict__ src, int ldk, int m0, int k0,
                                        int tid, float* sD) {
    const int m = tid >> 3, k4 = (tid & 7) * 4;
    #pragma unroll
    for (int pass = 0; pass < 2; ++pass) {
        int mm = m + pass * 32;
        float4 v = *reinterpret_cast<const float4*>(&src[(m0 + mm) * ldk + k0 + k4]);
        sD[(k4 + 0) * LDP + mm] = v.x; sD[(k4 + 1) * LDP + mm] = v.y;
        sD[(k4 + 2) * LDP + mm] = v.z; sD[(k4 + 3) * LDP + mm] = v.w;
    }
}
__device__ __forceinline__ void stage_T32(const float* __restrict__ src, int ldk, int m0, int k0,
                                          int tid, float* sD) {
    const int m = tid >> 3, k4 = (tid & 7) * 4;
    float4 v = *reinterpret_cast<const float4*>(&src[(m0 + m) * ldk + k0 + k4]);
    sD[(k4 + 0) * LDP + m] = v.x; sD[(k4 + 1) * LDP + m] = v.y;
    sD[(k4 + 2) * LDP + m] = v.z; sD[(k4 + 3) * LDP + m] = v.w;
}
__device__ __forceinline__ void stage_N1(const float* __restrict__ src, int ldn, int k0, int n0,
                                         int tid, float* sD) {
    const int k = tid >> 4, n4 = (tid & 15) * 4;
    #pragma unroll
    for (int pass = 0; pass < 2; ++pass) {
        int kk = k + pass * 16;
        *reinterpret_cast<float4*>(&sD[kk * LDP + n4]) =
            *reinterpret_cast<const float4*>(&src[(k0 + kk) * ldn + n0 + n4]);
    }
}
__device__ __forceinline__ void mm_inner(const float* sA, const float* sB, int tid, float acc[4][4]) {
    const int ty4 = (tid >> 4) * 4, tx4 = (tid & 15) * 4;
    #pragma unroll
    for (int kk = 0; kk < 32; ++kk) {
        float4 a4 = *reinterpret_cast<const float4*>(&sA[kk * LDP + ty4]);
        float4 b4 = *reinterpret_cast<const float4*>(&sB[kk * LDP + tx4]);
        FMA16(a4, b4, acc)
    }
}

// ---------------------------------------------------------------- KA (545 blocks):
//  t in [0,256)   : k1 - qp[ks] = hg@Wq^T partial, 64x64 tile, KS=8 (chunk 128)
//  t in [256,288) : M  - Mp[ks][f][d] = gk[d]*sum_e Uq[e,f]*Vk[e,d], 64x64, KS=2 (chunk 128)
//  t == 288       : vec4 chained matvecs + zero Sacc
//  t in [289,545) : per-p LN stats, one wave per p
__global__ __launch_bounds__(256) void KA(const float* __restrict__ hg, const float* __restrict__ Wq,
                                          const float* __restrict__ Uq, const float* __restrict__ Vk,
                                          const float* __restrict__ Ek, const float* __restrict__ Ev,
                                          const float* __restrict__ wk, const float* __restrict__ bk,
                                          const float* __restrict__ wv, const float* __restrict__ bv,
                                          const float* __restrict__ gk, const float* __restrict__ bkln,
                                          float* __restrict__ qp, float* __restrict__ Mp,
                                          float* __restrict__ Sacc,
                                          float* __restrict__ pst, float* __restrict__ scal4,
                                          float* __restrict__ vec4) {
    __shared__ __align__(16) float sA[32 * LDP];
    __shared__ __align__(16) float sB[32 * LDP];
    const int tid = threadIdx.x, t = blockIdx.x;
    const int ty4 = (tid >> 4) * 4, tx4 = (tid & 15) * 4;

    if (t < 256) {
        const int mt = t & 7, nt = (t >> 3) & 3, ks = t >> 5;
        const int b0 = mt * 64, d0 = nt * 64, kc = ks * 128;
        float acc[4][4] = {};
        for (int kt = 0; kt < 128; kt += 32) {
            stage_T(hg, DG, b0, kc + kt, tid, sA);
            stage_T(Wq, DG, d0, kc + kt, tid, sB);
            __syncthreads();
            mm_inner(sA, sB, tid, acc);
            __syncthreads();
        }
        float* outp = qp + ks * BD;
        #pragma unroll
        for (int i = 0; i < 4; ++i) {
            float4 o = make_float4(acc[i][0], acc[i][1], acc[i][2], acc[i][3]);
            *reinterpret_cast<float4*>(&outp[(b0 + ty4 + i) * DA + d0 + tx4]) = o;
        }
    } else if (t < 288) {
        // M[f][d] = gk[d] * sum_e Uq[e,f]*Vk[e,d]; A = Uq natural [e][f], B = Vk*gk natural [e][d]
        const int t2 = t - 256;
        const int ft = t2 & 3, dt = (t2 >> 2) & 3, ks = t2 >> 4;
        const int f0 = ft * 64, d0 = dt * 64, kc = ks * 128;
        const int k = tid >> 4, n4 = (tid & 15) * 4;
        float acc[4][4] = {};
        for (int kt = 0; kt < 128; kt += 32) {
            const int kg = kc + kt;
            stage_N1(Uq, DA, kg, f0, tid, sA);
            float4 g = *reinterpret_cast<const float4*>(&gk[d0 + n4]);
            #pragma unroll
            for (int pass = 0; pass < 2; ++pass) {
                int kk = k + pass * 16;
                float4 v = *reinterpret_cast<const float4*>(&Vk[(kg + kk) * DA + d0 + n4]);
                v.x *= g.x; v.y *= g.y; v.z *= g.z; v.w *= g.w;
                *reinterpret_cast<float4*>(&sB[kk * LDP + n4]) = v;
            }
            __syncthreads();
            mm_inner(sA, sB, tid, acc);
            __syncthreads();
        }
        float* outp = Mp + ks * (DA * DA);
        #pragma unroll
        for (int i = 0; i < 4; ++i) {
            float4 o = make_float4(acc[i][0], acc[i][1], acc[i][2], acc[i][3]);
            *reinterpret_cast<float4*>(&outp[(f0 + ty4 + i) * DA + d0 + tx4]) = o;
        }
    } else if (t == 288) {
        // zero the atomic scalar accumulators (4 x B)
        #pragma unroll
        for (int j = 0; j < 8; ++j) Sacc[j * 256 + tid] = 0.f;
        // vec4[j][f] = sum_e Uq[e,f] * (sum_d Vk[e,d]*w4[j][d])
        float* w4  = sA;   // [4][256]
        float* tmp = sB;   // [256][4]
        float gkd = gk[tid];
        w4[0 * 256 + tid] = wk[tid] * gkd;
        w4[1 * 256 + tid] = bk[tid] * gkd;
        w4[2 * 256 + tid] = gkd;
        w4[3 * 256 + tid] = bkln[tid];
        __syncthreads();
        const int dl = tid & 15, eg = tid >> 4;
        for (int eb = 0; eb < 16; ++eb) {
            int e = eb * 16 + eg;
            float p0 = 0.f, p1 = 0.f, p2 = 0.f, p3 = 0.f;
            #pragma unroll
            for (int tt = 0; tt < 16; ++tt) {
                int d = dl + tt * 16;
                float v = Vk[e * DA + d];
                p0 = fmaf(v, w4[d], p0);
                p1 = fmaf(v, w4[256 + d], p1);
                p2 = fmaf(v, w4[512 + d], p2);
                p3 = fmaf(v, w4[768 + d], p3);
            }
            #pragma unroll
            for (int m = 8; m > 0; m >>= 1) {
                p0 += __shfl_xor(p0, m, 16);
                p1 += __shfl_xor(p1, m, 16);
                p2 += __shfl_xor(p2, m, 16);
                p3 += __shfl_xor(p3, m, 16);
            }
            if (dl == 0) {
                tmp[e * 4 + 0] = p0; tmp[e * 4 + 1] = p1;
                tmp[e * 4 + 2] = p2; tmp[e * 4 + 3] = p3;
            }
        }
        __syncthreads();
        float a0 = 0.f, a1 = 0.f, a2 = 0.f, a3 = 0.f;
        for (int e = 0; e < 256; ++e) {
            float u = Uq[e * DA + tid];
            a0 = fmaf(u, tmp[e * 4 + 0], a0);
            a1 = fmaf(u, tmp[e * 4 + 1], a1);
            a2 = fmaf(u, tmp[e * 4 + 2], a2);
            a3 = fmaf(u, tmp[e * 4 + 3], a3);
        }
        vec4[tid] = a0; vec4[256 + tid] = a1; vec4[512 + tid] = a2; vec4[768 + tid] = a3;
    } else {
        // per-p LN stats, one wave per p
        const int tp = t - 289;
        const int wid = tid >> 6, lane = tid & 63;
        const int p = tp * 4 + wid;
        const int d4 = lane * 4;
        const float inv = 1.0f / DA;
        float4 ek4 = *reinterpret_cast<const float4*>(&Ek[p * DA + d4]);
        float4 ev4 = *reinterpret_cast<const float4*>(&Ev[p * DA + d4]);
        float4 wk4 = *reinterpret_cast<const float4*>(&wk[d4]);
        float4 bk4 = *reinterpret_cast<const float4*>(&bk[d4]);
        float4 wv4 = *reinterpret_cast<const float4*>(&wv[d4]);
        float4 bv4 = *reinterpret_cast<const float4*>(&bv[d4]);
        float ck0 = bk4.x + ek4.x, ck1 = bk4.y + ek4.y, ck2 = bk4.z + ek4.z, ck3 = bk4.w + ek4.w;
        float cv0 = bv4.x + ev4.x, cv1 = bv4.y + ev4.y, cv2 = bv4.z + ev4.z, cv3 = bv4.w + ev4.w;
        float Sck  = wsum(ck0 + ck1 + ck2 + ck3);
        float Sck2 = wsum(ck0*ck0 + ck1*ck1 + ck2*ck2 + ck3*ck3);
        float Swck = wsum(wk4.x*ck0 + wk4.y*ck1 + wk4.z*ck2 + wk4.w*ck3);
        float Scv  = wsum(cv0 + cv1 + cv2 + cv3);
        float Scv2 = wsum(cv0*cv0 + cv1*cv1 + cv2*cv2 + cv3*cv3);
        float Swcv = wsum(wv4.x*cv0 + wv4.y*cv1 + wv4.z*cv2 + wv4.w*cv3);
        float Swk  = wsum(wk4.x + wk4.y + wk4.z + wk4.w);
        float Swv  = wsum(wv4.x + wv4.y + wv4.z + wv4.w);
        float mwk = Swk * inv, mwv = Swv * inv;
        float mck = Sck * inv, mcv = Scv * inv;
        if (lane == 0) {
            pst[0 * P + p] = mck;
            pst[1 * P + p] = Swck * inv - mwk * mck;
            pst[2 * P + p] = Sck2 * inv - mck * mck;
            pst[3 * P + p] = mcv;
            pst[4 * P + p] = Swcv * inv - mwv * mcv;
            pst[5 * P + p] = Scv2 * inv - mcv * mcv;
        }
        if (p == 0) {
            float Swk2 = wsum(wk4.x*wk4.x + wk4.y*wk4.y + wk4.z*wk4.z + wk4.w*wk4.w);
            float Swv2 = wsum(wv4.x*wv4.x + wv4.y*wv4.y + wv4.z*wv4.z + wv4.w*wv4.w);
            if (lane == 0) {
                scal4[0] = mwk;
                scal4[1] = Swk2 * inv - mwk * mwk;
                scal4[2] = mwv;
                scal4[3] = Swv2 * inv - mwv * mwv;
            }
        }
    }
}

// ---------------------------------------------------------------- KC: per-b LN -> dots -> gr = q @ M (2 partials); zero out_c row
__global__ __launch_bounds__(256) void KC(const float* __restrict__ qp, const float* __restrict__ bq,
                                          const float* __restrict__ gq, const float* __restrict__ bqln,
                                          const float* __restrict__ vec4, const float* __restrict__ Mp,
                                          float* __restrict__ gr, float* __restrict__ bscal,
                                          float* __restrict__ out_c) {
    __shared__ __align__(16) float q_lds[DA];
    __shared__ float red[4];
    const int b = blockIdx.x, d = threadIdx.x;
    float x = bq[d];
    #pragma unroll
    for (int ks = 0; ks < 8; ++ks) x += qp[ks * BD + b * DA + d];
    float mu = block_reduce_sum(x, red) * (1.0f / DA);
    float xc = x - mu;
    float var = block_reduce_sum(xc * xc, red) * (1.0f / DA);
    float qv = xc * rsqrtf(var + 1e-5f) * gq[d] + bqln[d];
    q_lds[d] = qv;
    float Wg = block_reduce_sum(qv * vec4[d], red);        // also syncs q_lds
    float Cg = block_reduce_sum(qv * vec4[256 + d], red);
    float G_ = block_reduce_sum(qv * vec4[512 + d], red);
    float Bb = block_reduce_sum(qv * vec4[768 + d], red);
    if (d == 0) {
        bscal[b] = Wg; bscal[B + b] = Cg;
        bscal[2 * B + b] = G_; bscal[3 * B + b] = Bb;
    }
    out_c[b * DA + d] = 0.f;
    const float* M0 = Mp;
    const float* M1 = Mp + DA * DA;
    float grv = 0.f;
    for (int f = 0; f < DA; f += 4) {
        float4 qf = *reinterpret_cast<const float4*>(&q_lds[f]);
        grv = fmaf(qf.x, M0[(f + 0) * DA + d] + M1[(f + 0) * DA + d], grv);
        grv = fmaf(qf.y, M0[(f + 1) * DA + d] + M1[(f + 1) * DA + d], grv);
        grv = fmaf(qf.z, M0[(f + 2) * DA + d] + M1[(f + 2) * DA + d], grv);
        grv = fmaf(qf.w, M0[(f + 3) * DA + d] + M1[(f + 3) * DA + d], grv);
    }
    gr[b * DA + d] = grv;
}

// ---------------------------------------------------------------- KD: e = gr @ Ek^T (full K=256, 32x64 tile) + fused epilogue
// writes ubuf, wbuf; atomically accumulates Sacc[{S,SB,SBs,SBm}][b]
__global__ __launch_bounds__(256) void KD(const float* __restrict__ gr, const float* __restrict__ Ek,
                                          const float* __restrict__ desc, const float* __restrict__ bscal,
                                          const float* __restrict__ pst, const float* __restrict__ scal4,
                                          float* __restrict__ ubuf, float* __restrict__ wbuf,
                                          float* __restrict__ Sacc) {
    __shared__ __align__(16) float sA[32 * LDP];
    __shared__ __align__(16) float sB[32 * LDP];
    const int tid = threadIdx.x, t = blockIdx.x;
    const int tx = tid & 15, ty = tid >> 4;
    const int tx4 = tx * 4;
    const int b0 = (t & 15) * 32, p0 = (t >> 4) * 64;
    float acc[2][4] = {};
    for (int kt = 0; kt < 256; kt += 32) {
        stage_T32(gr, DA, b0, kt, tid, sA);              // gr[b][e] -> sA[e][b]
        stage_T(Ek, DA, p0, kt, tid, sB);                // Ek[p][e] -> sB[e][p]
        __syncthreads();
        #pragma unroll
        for (int kk = 0; kk < 32; ++kk) {
            float a0 = sA[kk * LDP + ty * 2 + 0];
            float a1 = sA[kk * LDP + ty * 2 + 1];
            float4 b4 = *reinterpret_cast<const float4*>(&sB[kk * LDP + tx4]);
            FMA8(a0, a1, b4, acc)
        }
        __syncthreads();
    }
    const float mwk = scal4[0], Ak = scal4[1], mwv = scal4[2], Av = scal4[3];
    #pragma unroll
    for (int i = 0; i < 2; ++i) {
        const int b = b0 + ty * 2 + i;
        const float Wg = bscal[b], Cg = bscal[B + b], G_ = bscal[2 * B + b], Bb = bscal[3 * B + b];
        float4 uo, wo;
        float* up = &uo.x; float* wp = &wo.x;
        float us = 0.f, ws_ = 0.f, wss = 0.f, wms = 0.f;
        #pragma unroll
        for (int j = 0; j < 4; ++j) {
            const int p = p0 + tx4 + j;
            float s = desc[b * P + p];
            float mck = pst[p], Bk = pst[P + p], Ck = pst[2 * P + p];
            float var = fmaf(s, fmaf(s, Ak, 2.0f * Bk), Ck);
            float rstd = rsqrtf(var + 1e-5f);
            float mu = fmaf(s, mwk, mck);
            float e = (rstd * (fmaf(s, Wg, Cg) + acc[i][j] - mu * G_) + Bb) * 0.0625f;
            float uu = 1.0f / (1.0f + expf(-e));
            float mcv = pst[3 * P + p], Bv = pst[4 * P + p], Cv = pst[5 * P + p];
            float varv = fmaf(s, fmaf(s, Av, 2.0f * Bv), Cv);
            float rv = rsqrtf(varv + 1e-5f);
            float ww = uu * rv;
            up[j] = uu; wp[j] = ww;
            us += uu; ws_ += ww;
            wss = fmaf(ww, s, wss);
            wms = fmaf(ww, fmaf(s, mwv, mcv), wms);
        }
        *reinterpret_cast<float4*>(&ubuf[b * P + p0 + tx4]) = uo;
        *reinterpret_cast<float4*>(&wbuf[b * P + p0 + tx4]) = wo;
        us = txsum(us); ws_ = txsum(ws_); wss = txsum(wss); wms = txsum(wms);
        if (tx == 0) {
            atomicAdd(&Sacc[b], us);
            atomicAdd(&Sacc[B + b], ws_);
            atomicAdd(&Sacc[2 * B + b], wss);
            atomicAdd(&Sacc[3 * B + b], wms);
        }
    }
}

// ---------------------------------------------------------------- KF: c += invS*gv*(w @ Ev) (atomic), base on ks==0, alpha on nt==0
__global__ __launch_bounds__(256) void KF(const float* __restrict__ ubuf, const float* __restrict__ wbuf,
                                          const float* __restrict__ Ev, const float* __restrict__ Sacc,
                                          const float* __restrict__ gv, const float* __restrict__ wv,
                                          const float* __restrict__ bvv, const float* __restrict__ bvln,
                                          float* __restrict__ out_c, float* __restrict__ alpha_out) {
    __shared__ __align__(16) float sA[32 * LDP];
    __shared__ __align__(16) float sB[32 * LDP];
    const int tid = threadIdx.x, t = blockIdx.x;
    const int ty4 = (tid >> 4) * 4, tx4 = (tid & 15) * 4;
    const int mt = t & 7, nt = (t >> 3) & 3, ks = t >> 5;
    const int b0 = mt * 64, d0 = nt * 64, kc = ks * 128;
    float acc[4][4] = {};
    for (int kt = 0; kt < 128; kt += 32) {
        stage_T(wbuf, P, b0, kc + kt, tid, sA);
        stage_N1(Ev, DA, kc + kt, d0, tid, sB);
        __syncthreads();
        mm_inner(sA, sB, tid, acc);
        __syncthreads();
    }
    float4 g4 = *reinterpret_cast<const float4*>(&gv[d0 + tx4]);
    float4 wv4 = *reinterpret_cast<const float4*>(&wv[d0 + tx4]);
    float4 bv4 = *reinterpret_cast<const float4*>(&bvv[d0 + tx4]);
    float4 bl4 = *reinterpret_cast<const float4*>(&bvln[d0 + tx4]);
    #pragma unroll
    for (int i = 0; i < 4; ++i) {
        const int b = b0 + ty4 + i;
        const float S = Sacc[b], SB = Sacc[B + b], SBs = Sacc[2 * B + b], SBm = Sacc[3 * B + b];
        const float invS = 1.0f / (S + 1e-12f);
        float v0 = acc[i][0] * invS * g4.x;
        float v1 = acc[i][1] * invS * g4.y;
        float v2 = acc[i][2] * invS * g4.z;
        float v3 = acc[i][3] * invS * g4.w;
        if (ks == 0) {
            const float T = S * invS;
            v0 += invS * g4.x * (wv4.x * SBs + bv4.x * SB - SBm) + bl4.x * T;
            v1 += invS * g4.y * (wv4.y * SBs + bv4.y * SB - SBm) + bl4.y * T;
            v2 += invS * g4.z * (wv4.z * SBs + bv4.z * SB - SBm) + bl4.z * T;
            v3 += invS * g4.w * (wv4.w * SBs + bv4.w * SB - SBm) + bl4.w * T;
        }
        float* dst = &out_c[b * DA + d0 + tx4];
        atomicAdd(dst + 0, v0);
        atomicAdd(dst + 1, v1);
        atomicAdd(dst + 2, v2);
        atomicAdd(dst + 3, v3);
    }
    if (nt == 0) {
        // alpha for b in [b0, b0+64), p in [kc, kc+128)
        #pragma unroll
        for (int r = 0; r < 32; ++r) {
            int idx = r * 256 + tid;
            int b = b0 + (idx >> 7);
            int p = kc + (idx & 127);
            float S = Sacc[b];
            alpha_out[b * P + p] = ubuf[b * P + p] / (S + 1e-12f);
        }
    }
}

// ---------------------------------------------------------------- launch
extern "C" void kernel_launch(void* const* d_in, const int* in_sizes, int n_in,
                              void* d_out, int out_size, void* d_ws, size_t ws_size,
                              hipStream_t stream) {
    (void)in_sizes; (void)n_in; (void)out_size; (void)ws_size;
    const float* hg   = (const float*)d_in[0];
    const float* desc = (const float*)d_in[1];
    const float* Wq   = (const float*)d_in[2];
    const float* bq   = (const float*)d_in[3];
    const float* wk   = (const float*)d_in[4];
    const float* bk   = (const float*)d_in[5];
    const float* wv   = (const float*)d_in[6];
    const float* bv   = (const float*)d_in[7];
    const float* Ek   = (const float*)d_in[8];
    const float* Ev   = (const float*)d_in[9];
    const float* Uq   = (const float*)d_in[10];
    const float* Vk   = (const float*)d_in[11];
    const float* gq   = (const float*)d_in[12];
    const float* bqln = (const float*)d_in[13];
    const float* gk   = (const float*)d_in[14];
    const float* bkln = (const float*)d_in[15];
    const float* gv   = (const float*)d_in[16];
    const float* bvln = (const float*)d_in[17];

    float* out = (float*)d_out;
    float* out_c = out;              // B*DA  (zeroed by KC, atomically accumulated by KF)
    float* out_alpha = out + BD;     // B*P   (written by KF nt==0 blocks)

    float* ws = (float*)d_ws;
    float* qp    = ws;               // 8 * BD   = 1048576
    float* Mp    = ws + 1048576;     // 2 * DA*DA = 131072
    float* gr    = ws + 1179648;     // 131072
    float* ubuf  = ws + 1310720;     // 524288
    float* wbuf  = ws + 1835008;     // 524288
    float* vec4  = ws + 2359296;     // 1024
    float* bscal = ws + 2360320;     // 2048
    float* Sacc  = ws + 2362368;     // 2048
    float* pst   = ws + 2364416;     // 6144
    float* scal4 = ws + 2370560;     // 4

    KA<<<545, 256, 0, stream>>>(hg, Wq, Uq, Vk, Ek, Ev, wk, bk, wv, bv, gk, bkln,
                                qp, Mp, Sacc, pst, scal4, vec4);
    KC<<<512, 256, 0, stream>>>(qp, bq, gq, bqln, vec4, Mp, gr, bscal, out_c);
    KD<<<256, 256, 0, stream>>>(gr, Ek, desc, bscal, pst, scal4, ubuf, wbuf, Sacc);
    KF<<<256, 256, 0, stream>>>(ubuf, wbuf, Ev, Sacc, gv, wv, bv, bvln, out_c, out_alpha);
}

// Round 12
// 70.467 us; speedup vs baseline: 1.1871x; 1.1871x over previous
//
#include <hip/hip_runtime.h>
#include <math.h>

#define B 512
#define DG 1024
#define P 1024
#define DA 256
#define LDP 68
#define BP (B * P)
#define BD (B * DA)

// ---------------------------------------------------------------- reductions
__device__ __forceinline__ float block_reduce_sum(float v, volatile float* red) {
    #pragma unroll
    for (int off = 32; off > 0; off >>= 1) v += __shfl_down(v, off, 64);
    const int lane = threadIdx.x & 63, wid = threadIdx.x >> 6;
    __syncthreads();
    if (lane == 0) red[wid] = v;
    __syncthreads();
    return red[0] + red[1] + red[2] + red[3];
}
__device__ __forceinline__ float wsum(float v) {
    #pragma unroll
    for (int m = 32; m > 0; m >>= 1) v += __shfl_xor(v, m, 64);
    return v;
}

#define FMA16(a4, b4, acc)                                   \
    acc[0][0] = fmaf(a4.x, b4.x, acc[0][0]);                 \
    acc[0][1] = fmaf(a4.x, b4.y, acc[0][1]);                 \
    acc[0][2] = fmaf(a4.x, b4.z, acc[0][2]);                 \
    acc[0][3] = fmaf(a4.x, b4.w, acc[0][3]);                 \
    acc[1][0] = fmaf(a4.y, b4.x, acc[1][0]);                 \
    acc[1][1] = fmaf(a4.y, b4.y, acc[1][1]);                 \
    acc[1][2] = fmaf(a4.y, b4.z, acc[1][2]);                 \
    acc[1][3] = fmaf(a4.y, b4.w, acc[1][3]);                 \
    acc[2][0] = fmaf(a4.z, b4.x, acc[2][0]);                 \
    acc[2][1] = fmaf(a4.z, b4.y, acc[2][1]);                 \
    acc[2][2] = fmaf(a4.z, b4.z, acc[2][2]);                 \
    acc[2][3] = fmaf(a4.z, b4.w, acc[2][3]);                 \
    acc[3][0] = fmaf(a4.w, b4.x, acc[3][0]);                 \
    acc[3][1] = fmaf(a4.w, b4.y, acc[3][1]);                 \
    acc[3][2] = fmaf(a4.w, b4.z, acc[3][2]);                 \
    acc[3][3] = fmaf(a4.w, b4.w, acc[3][3]);

// ---------------------------------------------------------------- staging helpers
__device__ __forceinline__ void stage_T(const float* __restrict__ src, int ldk, int m0, int k0,
                                        int tid, float* sD) {
    const int m = tid >> 3, k4 = (tid & 7) * 4;
    #pragma unroll
    for (int pass = 0; pass < 2; ++pass) {
        int mm = m + pass * 32;
        float4 v = *reinterpret_cast<const float4*>(&src[(m0 + mm) * ldk + k0 + k4]);
        sD[(k4 + 0) * LDP + mm] = v.x; sD[(k4 + 1) * LDP + mm] = v.y;
        sD[(k4 + 2) * LDP + mm] = v.z; sD[(k4 + 3) * LDP + mm] = v.w;
    }
}
__device__ __forceinline__ void stage_N1(const float* __restrict__ src, int ldn, int k0, int n0,
                                         int tid, float* sD) {
    const int k = tid >> 4, n4 = (tid & 15) * 4;
    #pragma unroll
    for (int pass = 0; pass < 2; ++pass) {
        int kk = k + pass * 16;
        *reinterpret_cast<float4*>(&sD[kk * LDP + n4]) =
            *reinterpret_cast<const float4*>(&src[(k0 + kk) * ldn + n0 + n4]);
    }
}
__device__ __forceinline__ void mm_inner(const float* sA, const float* sB, int tid, float acc[4][4]) {
    const int ty4 = (tid >> 4) * 4, tx4 = (tid & 15) * 4;
    #pragma unroll
    for (int kk = 0; kk < 32; ++kk) {
        float4 a4 = *reinterpret_cast<const float4*>(&sA[kk * LDP + ty4]);
        float4 b4 = *reinterpret_cast<const float4*>(&sB[kk * LDP + tx4]);
        FMA16(a4, b4, acc)
    }
}

// epilogue: from dot -> u (sigmoid) and w = u * rstd_v
__device__ __forceinline__ void epilog_uw(float dot, float s,
                                          float mck, float Bk, float Ck,
                                          float Bv, float Cv,
                                          float mwk, float Ak, float Av,
                                          float Wg, float Cg, float G_, float Bb,
                                          float& u, float& w) {
    float var = fmaf(s, fmaf(s, Ak, 2.0f * Bk), Ck);
    float rstd = rsqrtf(var + 1e-5f);
    float mu = fmaf(s, mwk, mck);
    float e = (rstd * (fmaf(s, Wg, Cg) + dot - mu * G_) + Bb) * 0.0625f;
    u = 1.0f / (1.0f + expf(-e));
    float varv = fmaf(s, fmaf(s, Av, 2.0f * Bv), Cv);
    w = u * rsqrtf(varv + 1e-5f);
}

// ---------------------------------------------------------------- KA (545 blocks):
//  t in [0,256)   : k1 - qp[ks] = hg@Wq^T partial, 64x64 tile, KS=8 (chunk 128)
//  t in [256,288) : M  - Mp[ks][f][d] = gk[d]*sum_e Uq[e,f]*Vk[e,d], 64x64, KS=2 (chunk 128)
//  t == 288       : vec4 chained matvecs
//  t in [289,545) : per-p LN stats, one wave per p
__global__ __launch_bounds__(256) void KA(const float* __restrict__ hg, const float* __restrict__ Wq,
                                          const float* __restrict__ Uq, const float* __restrict__ Vk,
                                          const float* __restrict__ Ek, const float* __restrict__ Ev,
                                          const float* __restrict__ wk, const float* __restrict__ bk,
                                          const float* __restrict__ wv, const float* __restrict__ bv,
                                          const float* __restrict__ gk, const float* __restrict__ bkln,
                                          float* __restrict__ qp, float* __restrict__ Mp,
                                          float* __restrict__ pst, float* __restrict__ scal4,
                                          float* __restrict__ vec4) {
    __shared__ __align__(16) float sA[32 * LDP];
    __shared__ __align__(16) float sB[32 * LDP];
    const int tid = threadIdx.x, t = blockIdx.x;
    const int ty4 = (tid >> 4) * 4, tx4 = (tid & 15) * 4;

    if (t < 256) {
        const int mt = t & 7, nt = (t >> 3) & 3, ks = t >> 5;
        const int b0 = mt * 64, d0 = nt * 64, kc = ks * 128;
        float acc[4][4] = {};
        for (int kt = 0; kt < 128; kt += 32) {
            stage_T(hg, DG, b0, kc + kt, tid, sA);
            stage_T(Wq, DG, d0, kc + kt, tid, sB);
            __syncthreads();
            mm_inner(sA, sB, tid, acc);
            __syncthreads();
        }
        float* outp = qp + ks * BD;
        #pragma unroll
        for (int i = 0; i < 4; ++i) {
            float4 o = make_float4(acc[i][0], acc[i][1], acc[i][2], acc[i][3]);
            *reinterpret_cast<float4*>(&outp[(b0 + ty4 + i) * DA + d0 + tx4]) = o;
        }
    } else if (t < 288) {
        // M[f][d] = gk[d] * sum_e Uq[e,f]*Vk[e,d]; A = Uq natural [e][f], B = Vk*gk natural [e][d]
        const int t2 = t - 256;
        const int ft = t2 & 3, dt = (t2 >> 2) & 3, ks = t2 >> 4;
        const int f0 = ft * 64, d0 = dt * 64, kc = ks * 128;
        const int k = tid >> 4, n4 = (tid & 15) * 4;
        float acc[4][4] = {};
        for (int kt = 0; kt < 128; kt += 32) {
            const int kg = kc + kt;
            stage_N1(Uq, DA, kg, f0, tid, sA);
            float4 g = *reinterpret_cast<const float4*>(&gk[d0 + n4]);
            #pragma unroll
            for (int pass = 0; pass < 2; ++pass) {
                int kk = k + pass * 16;
                float4 v = *reinterpret_cast<const float4*>(&Vk[(kg + kk) * DA + d0 + n4]);
                v.x *= g.x; v.y *= g.y; v.z *= g.z; v.w *= g.w;
                *reinterpret_cast<float4*>(&sB[kk * LDP + n4]) = v;
            }
            __syncthreads();
            mm_inner(sA, sB, tid, acc);
            __syncthreads();
        }
        float* outp = Mp + ks * (DA * DA);
        #pragma unroll
        for (int i = 0; i < 4; ++i) {
            float4 o = make_float4(acc[i][0], acc[i][1], acc[i][2], acc[i][3]);
            *reinterpret_cast<float4*>(&outp[(f0 + ty4 + i) * DA + d0 + tx4]) = o;
        }
    } else if (t == 288) {
        // vec4[j][f] = sum_e Uq[e,f] * (sum_d Vk[e,d]*w4[j][d])
        float* w4  = sA;   // [4][256]
        float* tmp = sB;   // [256][4]
        float gkd = gk[tid];
        w4[0 * 256 + tid] = wk[tid] * gkd;
        w4[1 * 256 + tid] = bk[tid] * gkd;
        w4[2 * 256 + tid] = gkd;
        w4[3 * 256 + tid] = bkln[tid];
        __syncthreads();
        const int dl = tid & 15, eg = tid >> 4;
        for (int eb = 0; eb < 16; ++eb) {
            int e = eb * 16 + eg;
            float p0 = 0.f, p1 = 0.f, p2 = 0.f, p3 = 0.f;
            #pragma unroll
            for (int tt = 0; tt < 16; ++tt) {
                int d = dl + tt * 16;
                float v = Vk[e * DA + d];
                p0 = fmaf(v, w4[d], p0);
                p1 = fmaf(v, w4[256 + d], p1);
                p2 = fmaf(v, w4[512 + d], p2);
                p3 = fmaf(v, w4[768 + d], p3);
            }
            #pragma unroll
            for (int m = 8; m > 0; m >>= 1) {
                p0 += __shfl_xor(p0, m, 16);
                p1 += __shfl_xor(p1, m, 16);
                p2 += __shfl_xor(p2, m, 16);
                p3 += __shfl_xor(p3, m, 16);
            }
            if (dl == 0) {
                tmp[e * 4 + 0] = p0; tmp[e * 4 + 1] = p1;
                tmp[e * 4 + 2] = p2; tmp[e * 4 + 3] = p3;
            }
        }
        __syncthreads();
        float a0 = 0.f, a1 = 0.f, a2 = 0.f, a3 = 0.f;
        for (int e = 0; e < 256; ++e) {
            float u = Uq[e * DA + tid];
            a0 = fmaf(u, tmp[e * 4 + 0], a0);
            a1 = fmaf(u, tmp[e * 4 + 1], a1);
            a2 = fmaf(u, tmp[e * 4 + 2], a2);
            a3 = fmaf(u, tmp[e * 4 + 3], a3);
        }
        vec4[tid] = a0; vec4[256 + tid] = a1; vec4[512 + tid] = a2; vec4[768 + tid] = a3;
    } else {
        // per-p LN stats, one wave per p
        const int tp = t - 289;
        const int wid = tid >> 6, lane = tid & 63;
        const int p = tp * 4 + wid;
        const int d4 = lane * 4;
        const float inv = 1.0f / DA;
        float4 ek4 = *reinterpret_cast<const float4*>(&Ek[p * DA + d4]);
        float4 ev4 = *reinterpret_cast<const float4*>(&Ev[p * DA + d4]);
        float4 wk4 = *reinterpret_cast<const float4*>(&wk[d4]);
        float4 bk4 = *reinterpret_cast<const float4*>(&bk[d4]);
        float4 wv4 = *reinterpret_cast<const float4*>(&wv[d4]);
        float4 bv4 = *reinterpret_cast<const float4*>(&bv[d4]);
        float ck0 = bk4.x + ek4.x, ck1 = bk4.y + ek4.y, ck2 = bk4.z + ek4.z, ck3 = bk4.w + ek4.w;
        float cv0 = bv4.x + ev4.x, cv1 = bv4.y + ev4.y, cv2 = bv4.z + ev4.z, cv3 = bv4.w + ev4.w;
        float Sck  = wsum(ck0 + ck1 + ck2 + ck3);
        float Sck2 = wsum(ck0*ck0 + ck1*ck1 + ck2*ck2 + ck3*ck3);
        float Swck = wsum(wk4.x*ck0 + wk4.y*ck1 + wk4.z*ck2 + wk4.w*ck3);
        float Scv  = wsum(cv0 + cv1 + cv2 + cv3);
        float Scv2 = wsum(cv0*cv0 + cv1*cv1 + cv2*cv2 + cv3*cv3);
        float Swcv = wsum(wv4.x*cv0 + wv4.y*cv1 + wv4.z*cv2 + wv4.w*cv3);
        float Swk  = wsum(wk4.x + wk4.y + wk4.z + wk4.w);
        float Swv  = wsum(wv4.x + wv4.y + wv4.z + wv4.w);
        float mwk = Swk * inv, mwv = Swv * inv;
        float mck = Sck * inv, mcv = Scv * inv;
        if (lane == 0) {
            pst[0 * P + p] = mck;
            pst[1 * P + p] = Swck * inv - mwk * mck;
            pst[2 * P + p] = Sck2 * inv - mck * mck;
            pst[3 * P + p] = mcv;
            pst[4 * P + p] = Swcv * inv - mwv * mcv;
            pst[5 * P + p] = Scv2 * inv - mcv * mcv;
        }
        if (p == 0) {
            float Swk2 = wsum(wk4.x*wk4.x + wk4.y*wk4.y + wk4.z*wk4.z + wk4.w*wk4.w);
            float Swv2 = wsum(wv4.x*wv4.x + wv4.y*wv4.y + wv4.z*wv4.z + wv4.w*wv4.w);
            if (lane == 0) {
                scal4[0] = mwk;
                scal4[1] = Swk2 * inv - mwk * mwk;
                scal4[2] = mwv;
                scal4[3] = Swv2 * inv - mwv * mwv;
            }
        }
    }
}

// ---------------------------------------------------------------- KC: per-b LN -> vec4 dots -> gr = q @ (M0+M1)
__global__ __launch_bounds__(256) void KC(const float* __restrict__ qp, const float* __restrict__ bq,
                                          const float* __restrict__ gq, const float* __restrict__ bqln,
                                          const float* __restrict__ vec4, const float* __restrict__ Mp,
                                          float* __restrict__ gr, float* __restrict__ bscal) {
    __shared__ __align__(16) float q_lds[DA];
    __shared__ float red[4];
    const int b = blockIdx.x, d = threadIdx.x;
    float x = bq[d];
    #pragma unroll
    for (int ks = 0; ks < 8; ++ks) x += qp[ks * BD + b * DA + d];
    float mu = block_reduce_sum(x, red) * (1.0f / DA);
    float xc = x - mu;
    float var = block_reduce_sum(xc * xc, red) * (1.0f / DA);
    float qv = xc * rsqrtf(var + 1e-5f) * gq[d] + bqln[d];
    q_lds[d] = qv;
    float Wg = block_reduce_sum(qv * vec4[d], red);        // also syncs q_lds
    float Cg = block_reduce_sum(qv * vec4[256 + d], red);
    float G_ = block_reduce_sum(qv * vec4[512 + d], red);
    float Bb = block_reduce_sum(qv * vec4[768 + d], red);
    if (d == 0) {
        bscal[b] = Wg; bscal[B + b] = Cg;
        bscal[2 * B + b] = G_; bscal[3 * B + b] = Bb;
    }
    const float* M0 = Mp;
    const float* M1 = Mp + DA * DA;
    float grv = 0.f;
    for (int f = 0; f < DA; f += 4) {
        float4 qf = *reinterpret_cast<const float4*>(&q_lds[f]);
        grv = fmaf(qf.x, M0[(f + 0) * DA + d] + M1[(f + 0) * DA + d], grv);
        grv = fmaf(qf.y, M0[(f + 1) * DA + d] + M1[(f + 1) * DA + d], grv);
        grv = fmaf(qf.z, M0[(f + 2) * DA + d] + M1[(f + 2) * DA + d], grv);
        grv = fmaf(qf.w, M0[(f + 3) * DA + d] + M1[(f + 3) * DA + d], grv);
    }
    gr[b * DA + d] = grv;
}

// ---------------------------------------------------------------- KD: epart[ks] = gr @ Ek^T, KS=2 (chunk 128), R3/R10 config
__global__ __launch_bounds__(256) void KD(const float* __restrict__ gr, const float* __restrict__ Ek,
                                          float* __restrict__ epart) {
    __shared__ __align__(16) float sA[32 * LDP];
    __shared__ __align__(16) float sB[32 * LDP];
    const int tid = threadIdx.x, t = blockIdx.x;
    const int ty4 = (tid >> 4) * 4, tx4 = (tid & 15) * 4;
    const int mt = t & 7, nt = (t >> 3) & 15, ks = t >> 7;
    const int b0 = mt * 64, p0 = nt * 64, kc = ks * 128;
    float acc[4][4] = {};
    for (int kt = 0; kt < 128; kt += 32) {
        stage_T(gr, DA, b0, kc + kt, tid, sA);
        stage_T(Ek, DA, p0, kc + kt, tid, sB);
        __syncthreads();
        mm_inner(sA, sB, tid, acc);
        __syncthreads();
    }
    float* outp = epart + ks * BP;
    #pragma unroll
    for (int i = 0; i < 4; ++i) {
        float4 o = make_float4(acc[i][0], acc[i][1], acc[i][2], acc[i][3]);
        *reinterpret_cast<float4*>(&outp[(b0 + ty4 + i) * P + p0 + tx4]) = o;
    }
}

// ---------------------------------------------------------------- KF: cpart[ks] = w @ Ev, KS=8 (chunk 128); w computed in A-staging
__global__ __launch_bounds__(256) void KF(const float* __restrict__ epart, const float* __restrict__ desc,
                                          const float* __restrict__ bscal, const float* __restrict__ pst,
                                          const float* __restrict__ scal4, const float* __restrict__ Ev,
                                          float* __restrict__ cpart) {
    __shared__ __align__(16) float sA[32 * LDP];
    __shared__ __align__(16) float sB[32 * LDP];
    const int tid = threadIdx.x, t = blockIdx.x;
    const int ty4 = (tid >> 4) * 4, tx4 = (tid & 15) * 4;
    const int mt = t & 7, nt = (t >> 3) & 3, ks = t >> 5;
    const int b0 = mt * 64, d0 = nt * 64, kc = ks * 128;
    const float mwk = scal4[0], Ak = scal4[1], Av = scal4[3];
    const int m = tid >> 3, k4 = (tid & 7) * 4;
    float acc[4][4] = {};
    for (int kt = 0; kt < 128; kt += 32) {
        const int kg = kc + kt;   // p-offset of this 32-slice
        // ---- A-stage: compute w[b][p] on the fly -> sA[p][b]
        #pragma unroll
        for (int pass = 0; pass < 2; ++pass) {
            int mm = m + pass * 32;
            const int b = b0 + mm;
            const int p = kg + k4;
            float4 e0 = *reinterpret_cast<const float4*>(&epart[b * P + p]);
            float4 e1 = *reinterpret_cast<const float4*>(&epart[BP + b * P + p]);
            float4 s4 = *reinterpret_cast<const float4*>(&desc[b * P + p]);
            float4 mck4 = *reinterpret_cast<const float4*>(&pst[p]);
            float4 Bk4  = *reinterpret_cast<const float4*>(&pst[P + p]);
            float4 Ck4  = *reinterpret_cast<const float4*>(&pst[2 * P + p]);
            float4 Bv4  = *reinterpret_cast<const float4*>(&pst[4 * P + p]);
            float4 Cv4  = *reinterpret_cast<const float4*>(&pst[5 * P + p]);
            const float Wg = bscal[b], Cg = bscal[B + b];
            const float G_ = bscal[2 * B + b], Bb = bscal[3 * B + b];
            float u, w;
            epilog_uw(e0.x + e1.x, s4.x, mck4.x, Bk4.x, Ck4.x, Bv4.x, Cv4.x,
                      mwk, Ak, Av, Wg, Cg, G_, Bb, u, w);
            sA[(k4 + 0) * LDP + mm] = w;
            epilog_uw(e0.y + e1.y, s4.y, mck4.y, Bk4.y, Ck4.y, Bv4.y, Cv4.y,
                      mwk, Ak, Av, Wg, Cg, G_, Bb, u, w);
            sA[(k4 + 1) * LDP + mm] = w;
            epilog_uw(e0.z + e1.z, s4.z, mck4.z, Bk4.z, Ck4.z, Bv4.z, Cv4.z,
                      mwk, Ak, Av, Wg, Cg, G_, Bb, u, w);
            sA[(k4 + 2) * LDP + mm] = w;
            epilog_uw(e0.w + e1.w, s4.w, mck4.w, Bk4.w, Ck4.w, Bv4.w, Cv4.w,
                      mwk, Ak, Av, Wg, Cg, G_, Bb, u, w);
            sA[(k4 + 3) * LDP + mm] = w;
        }
        stage_N1(Ev, DA, kg, d0, tid, sB);
        __syncthreads();
        mm_inner(sA, sB, tid, acc);
        __syncthreads();
    }
    float* outp = cpart + ks * BD;
    #pragma unroll
    for (int i = 0; i < 4; ++i) {
        float4 o = make_float4(acc[i][0], acc[i][1], acc[i][2], acc[i][3]);
        *reinterpret_cast<float4*>(&outp[(b0 + ty4 + i) * DA + d0 + tx4]) = o;
    }
}

// ---------------------------------------------------------------- KG: per-b full epilogue: u,w -> scalars -> alpha, final c
__global__ __launch_bounds__(256) void KG(const float* __restrict__ epart, const float* __restrict__ desc,
                                          const float* __restrict__ bscal, const float* __restrict__ pst,
                                          const float* __restrict__ scal4, const float* __restrict__ cpart,
                                          const float* __restrict__ gv, const float* __restrict__ wv,
                                          const float* __restrict__ bvv, const float* __restrict__ bvln,
                                          float* __restrict__ alpha_out, float* __restrict__ out_c) {
    __shared__ float red[4];
    const int b = blockIdx.x, tid = threadIdx.x;
    const float mwk = scal4[0], Ak = scal4[1], mwv = scal4[2], Av = scal4[3];
    const float Wg = bscal[b], Cg = bscal[B + b], G_ = bscal[2 * B + b], Bb = bscal[3 * B + b];
    float u[4];
    float us = 0.f, ws_ = 0.f, wss = 0.f, wms = 0.f;
    #pragma unroll
    for (int j = 0; j < 4; ++j) {
        int p = j * 256 + tid;
        float dot = epart[b * P + p] + epart[BP + b * P + p];
        float s = desc[b * P + p];
        float uu, ww;
        epilog_uw(dot, s, pst[p], pst[P + p], pst[2 * P + p], pst[4 * P + p], pst[5 * P + p],
                  mwk, Ak, Av, Wg, Cg, G_, Bb, uu, ww);
        u[j] = uu;
        us += uu; ws_ += ww;
        wss = fmaf(ww, s, wss);
        wms = fmaf(ww, fmaf(s, mwv, pst[3 * P + p]), wms);
    }
    float S   = block_reduce_sum(us, red);
    float SB  = block_reduce_sum(ws_, red);
    float SBs = block_reduce_sum(wss, red);
    float SBm = block_reduce_sum(wms, red);
    float invS = 1.0f / (S + 1e-12f);
    float T = S * invS;
    #pragma unroll
    for (int j = 0; j < 4; ++j)
        alpha_out[b * P + j * 256 + tid] = u[j] * invS;
    const int d = tid;
    float csum = 0.f;
    #pragma unroll
    for (int ks = 0; ks < 8; ++ks) csum += cpart[ks * BD + b * DA + d];
    out_c[b * DA + d] =
        invS * (gv[d] * (wv[d] * SBs + bvv[d] * SB + csum - SBm)) + bvln[d] * T;
}

// ---------------------------------------------------------------- launch
extern "C" void kernel_launch(void* const* d_in, const int* in_sizes, int n_in,
                              void* d_out, int out_size, void* d_ws, size_t ws_size,
                              hipStream_t stream) {
    (void)in_sizes; (void)n_in; (void)out_size; (void)ws_size;
    const float* hg   = (const float*)d_in[0];
    const float* desc = (const float*)d_in[1];
    const float* Wq   = (const float*)d_in[2];
    const float* bq   = (const float*)d_in[3];
    const float* wk   = (const float*)d_in[4];
    const float* bk   = (const float*)d_in[5];
    const float* wv   = (const float*)d_in[6];
    const float* bv   = (const float*)d_in[7];
    const float* Ek   = (const float*)d_in[8];
    const float* Ev   = (const float*)d_in[9];
    const float* Uq   = (const float*)d_in[10];
    const float* Vk   = (const float*)d_in[11];
    const float* gq   = (const float*)d_in[12];
    const float* bqln = (const float*)d_in[13];
    const float* gk   = (const float*)d_in[14];
    const float* bkln = (const float*)d_in[15];
    const float* gv   = (const float*)d_in[16];
    const float* bvln = (const float*)d_in[17];

    float* out = (float*)d_out;
    float* out_c = out;              // B*DA
    float* out_alpha = out + BD;     // B*P

    float* ws = (float*)d_ws;
    float* qp    = ws;               // 8 * BD    = 1048576
    float* Mp    = ws + 1048576;     // 2 * DA*DA = 131072
    float* gr    = ws + 1179648;     // 131072
    float* epart = ws + 1310720;     // 2 * BP    = 1048576
    float* cpart = ws + 2359296;     // 8 * BD    = 1048576
    float* vec4  = ws + 3407872;     // 1024
    float* bscal = ws + 3408896;     // 2048
    float* pst   = ws + 3410944;     // 6144
    float* scal4 = ws + 3417088;     // 4

    KA<<<545, 256, 0, stream>>>(hg, Wq, Uq, Vk, Ek, Ev, wk, bk, wv, bv, gk, bkln,
                                qp, Mp, pst, scal4, vec4);
    KC<<<512, 256, 0, stream>>>(qp, bq, gq, bqln, vec4, Mp, gr, bscal);
    KD<<<256, 256, 0, stream>>>(gr, Ek, epart);
    KF<<<256, 256, 0, stream>>>(epart, desc, bscal, pst, scal4, Ev, cpart);
    KG<<<512, 256, 0, stream>>>(epart, desc, bscal, pst, scal4, cpart, gv, wv, bv, bvln,
                                out_alpha, out_c);
}

// Round 13
// 57.414 us; speedup vs baseline: 1.4570x; 1.2273x over previous
//
#include <hip/hip_runtime.h>
#include <math.h>

#define B 512
#define DG 1024
#define P 1024
#define DA 256
#define LDP 68
#define BP (B * P)
#define BD (B * DA)

// ---------------------------------------------------------------- reductions
__device__ __forceinline__ float block_reduce_sum(float v, volatile float* red) {
    #pragma unroll
    for (int off = 32; off > 0; off >>= 1) v += __shfl_down(v, off, 64);
    const int lane = threadIdx.x & 63, wid = threadIdx.x >> 6;
    __syncthreads();
    if (lane == 0) red[wid] = v;
    __syncthreads();
    return red[0] + red[1] + red[2] + red[3];
}
__device__ __forceinline__ float wsum(float v) {
    #pragma unroll
    for (int m = 32; m > 0; m >>= 1) v += __shfl_xor(v, m, 64);
    return v;
}

#define FMA16(a4, b4, acc)                                   \
    acc[0][0] = fmaf(a4.x, b4.x, acc[0][0]);                 \
    acc[0][1] = fmaf(a4.x, b4.y, acc[0][1]);                 \
    acc[0][2] = fmaf(a4.x, b4.z, acc[0][2]);                 \
    acc[0][3] = fmaf(a4.x, b4.w, acc[0][3]);                 \
    acc[1][0] = fmaf(a4.y, b4.x, acc[1][0]);                 \
    acc[1][1] = fmaf(a4.y, b4.y, acc[1][1]);                 \
    acc[1][2] = fmaf(a4.y, b4.z, acc[1][2]);                 \
    acc[1][3] = fmaf(a4.y, b4.w, acc[1][3]);                 \
    acc[2][0] = fmaf(a4.z, b4.x, acc[2][0]);                 \
    acc[2][1] = fmaf(a4.z, b4.y, acc[2][1]);                 \
    acc[2][2] = fmaf(a4.z, b4.z, acc[2][2]);                 \
    acc[2][3] = fmaf(a4.z, b4.w, acc[2][3]);                 \
    acc[3][0] = fmaf(a4.w, b4.x, acc[3][0]);                 \
    acc[3][1] = fmaf(a4.w, b4.y, acc[3][1]);                 \
    acc[3][2] = fmaf(a4.w, b4.z, acc[3][2]);                 \
    acc[3][3] = fmaf(a4.w, b4.w, acc[3][3]);

// ---------------------------------------------------------------- staging helpers
__device__ __forceinline__ void stage_T(const float* __restrict__ src, int ldk, int m0, int k0,
                                        int tid, float* sD) {
    const int m = tid >> 3, k4 = (tid & 7) * 4;
    #pragma unroll
    for (int pass = 0; pass < 2; ++pass) {
        int mm = m + pass * 32;
        float4 v = *reinterpret_cast<const float4*>(&src[(m0 + mm) * ldk + k0 + k4]);
        sD[(k4 + 0) * LDP + mm] = v.x; sD[(k4 + 1) * LDP + mm] = v.y;
        sD[(k4 + 2) * LDP + mm] = v.z; sD[(k4 + 3) * LDP + mm] = v.w;
    }
}
__device__ __forceinline__ void stage_N1(const float* __restrict__ src, int ldn, int k0, int n0,
                                         int tid, float* sD) {
    const int k = tid >> 4, n4 = (tid & 15) * 4;
    #pragma unroll
    for (int pass = 0; pass < 2; ++pass) {
        int kk = k + pass * 16;
        *reinterpret_cast<float4*>(&sD[kk * LDP + n4]) =
            *reinterpret_cast<const float4*>(&src[(k0 + kk) * ldn + n0 + n4]);
    }
}
__device__ __forceinline__ void mm_inner(const float* sA, const float* sB, int tid, float acc[4][4]) {
    const int ty4 = (tid >> 4) * 4, tx4 = (tid & 15) * 4;
    #pragma unroll
    for (int kk = 0; kk < 32; ++kk) {
        float4 a4 = *reinterpret_cast<const float4*>(&sA[kk * LDP + ty4]);
        float4 b4 = *reinterpret_cast<const float4*>(&sB[kk * LDP + tx4]);
        FMA16(a4, b4, acc)
    }
}

// epilogue: from dot -> u (sigmoid) and w = u * rstd_v
__device__ __forceinline__ void epilog_uw(float dot, float s,
                                          float mck, float Bk, float Ck,
                                          float Bv, float Cv,
                                          float mwk, float Ak, float Av,
                                          float Wg, float Cg, float G_, float Bb,
                                          float& u, float& w) {
    float var = fmaf(s, fmaf(s, Ak, 2.0f * Bk), Ck);
    float rstd = rsqrtf(var + 1e-5f);
    float mu = fmaf(s, mwk, mck);
    float e = (rstd * (fmaf(s, Wg, Cg) + dot - mu * G_) + Bb) * 0.0625f;
    u = 1.0f / (1.0f + expf(-e));
    float varv = fmaf(s, fmaf(s, Av, 2.0f * Bv), Cv);
    w = u * rsqrtf(varv + 1e-5f);
}

// ---------------------------------------------------------------- KA (576 blocks):
//  t in [0,256)   : k1 - qp[ks] = hg@Wq^T partial, 64x64 tile, KS=8 (chunk 128)
//  t in [256,320) : UqT transpose
//  t in [320,576) : per-p LN stats, one wave per p
__global__ __launch_bounds__(256) void KA(const float* __restrict__ hg, const float* __restrict__ Wq,
                                          const float* __restrict__ Uq,
                                          const float* __restrict__ Ek, const float* __restrict__ Ev,
                                          const float* __restrict__ wk, const float* __restrict__ bk,
                                          const float* __restrict__ wv, const float* __restrict__ bv,
                                          float* __restrict__ qp, float* __restrict__ UqT,
                                          float* __restrict__ pst, float* __restrict__ scal4) {
    __shared__ __align__(16) float sA[32 * LDP];
    __shared__ __align__(16) float sB[32 * LDP];
    const int tid = threadIdx.x, t = blockIdx.x;
    const int ty4 = (tid >> 4) * 4, tx4 = (tid & 15) * 4;

    if (t < 256) {
        const int mt = t & 7, nt = (t >> 3) & 3, ks = t >> 5;
        const int b0 = mt * 64, d0 = nt * 64, kc = ks * 128;
        float acc[4][4] = {};
        for (int kt = 0; kt < 128; kt += 32) {
            stage_T(hg, DG, b0, kc + kt, tid, sA);
            stage_T(Wq, DG, d0, kc + kt, tid, sB);
            __syncthreads();
            mm_inner(sA, sB, tid, acc);
            __syncthreads();
        }
        float* outp = qp + ks * BD;
        #pragma unroll
        for (int i = 0; i < 4; ++i) {
            float4 o = make_float4(acc[i][0], acc[i][1], acc[i][2], acc[i][3]);
            *reinterpret_cast<float4*>(&outp[(b0 + ty4 + i) * DA + d0 + tx4]) = o;
        }
    } else if (t < 320) {
        const int b2 = t - 256;
        const int e0 = (b2 & 7) * 32, f0 = (b2 >> 3) * 32;
        const int col = tid & 31, row8 = tid >> 5;
        #pragma unroll
        for (int pass = 0; pass < 4; ++pass) {
            int r = row8 + pass * 8;
            sA[r * 33 + col] = Uq[(e0 + r) * DA + f0 + col];
        }
        __syncthreads();
        #pragma unroll
        for (int pass = 0; pass < 4; ++pass) {
            int r = row8 + pass * 8;
            UqT[(f0 + r) * DA + e0 + col] = sA[col * 33 + r];
        }
    } else {
        // per-p LN stats, one wave per p
        const int tp = t - 320;
        const int wid = tid >> 6, lane = tid & 63;
        const int p = tp * 4 + wid;
        const int d4 = lane * 4;
        const float inv = 1.0f / DA;
        float4 ek4 = *reinterpret_cast<const float4*>(&Ek[p * DA + d4]);
        float4 ev4 = *reinterpret_cast<const float4*>(&Ev[p * DA + d4]);
        float4 wk4 = *reinterpret_cast<const float4*>(&wk[d4]);
        float4 bk4 = *reinterpret_cast<const float4*>(&bk[d4]);
        float4 wv4 = *reinterpret_cast<const float4*>(&wv[d4]);
        float4 bv4 = *reinterpret_cast<const float4*>(&bv[d4]);
        float ck0 = bk4.x + ek4.x, ck1 = bk4.y + ek4.y, ck2 = bk4.z + ek4.z, ck3 = bk4.w + ek4.w;
        float cv0 = bv4.x + ev4.x, cv1 = bv4.y + ev4.y, cv2 = bv4.z + ev4.z, cv3 = bv4.w + ev4.w;
        float Sck  = wsum(ck0 + ck1 + ck2 + ck3);
        float Sck2 = wsum(ck0*ck0 + ck1*ck1 + ck2*ck2 + ck3*ck3);
        float Swck = wsum(wk4.x*ck0 + wk4.y*ck1 + wk4.z*ck2 + wk4.w*ck3);
        float Scv  = wsum(cv0 + cv1 + cv2 + cv3);
        float Scv2 = wsum(cv0*cv0 + cv1*cv1 + cv2*cv2 + cv3*cv3);
        float Swcv = wsum(wv4.x*cv0 + wv4.y*cv1 + wv4.z*cv2 + wv4.w*cv3);
        float Swk  = wsum(wk4.x + wk4.y + wk4.z + wk4.w);
        float Swv  = wsum(wv4.x + wv4.y + wv4.z + wv4.w);
        float mwk = Swk * inv, mwv = Swv * inv;
        float mck = Sck * inv, mcv = Scv * inv;
        if (lane == 0) {
            pst[0 * P + p] = mck;
            pst[1 * P + p] = Swck * inv - mwk * mck;
            pst[2 * P + p] = Sck2 * inv - mck * mck;
            pst[3 * P + p] = mcv;
            pst[4 * P + p] = Swcv * inv - mwv * mcv;
            pst[5 * P + p] = Scv2 * inv - mcv * mcv;
        }
        if (p == 0) {
            float Swk2 = wsum(wk4.x*wk4.x + wk4.y*wk4.y + wk4.z*wk4.z + wk4.w*wk4.w);
            float Swv2 = wsum(wv4.x*wv4.x + wv4.y*wv4.y + wv4.z*wv4.z + wv4.w*wv4.w);
            if (lane == 0) {
                scal4[0] = mwk;
                scal4[1] = Swk2 * inv - mwk * mwk;
                scal4[2] = mwv;
                scal4[3] = Swv2 * inv - mwv * mwv;
            }
        }
    }
}

// ---------------------------------------------------------------- KC: per-b LN -> q2 -> r -> gr + bscal  (R3-verified)
__global__ __launch_bounds__(256) void KC(const float* __restrict__ qp, const float* __restrict__ bq,
                                          const float* __restrict__ gq, const float* __restrict__ bqln,
                                          const float* __restrict__ UqT, const float* __restrict__ Vk,
                                          const float* __restrict__ gk,
                                          const float* __restrict__ wk, const float* __restrict__ bk,
                                          const float* __restrict__ bkln,
                                          float* __restrict__ gr, float* __restrict__ bscal) {
    __shared__ __align__(16) float q_lds[DA];
    __shared__ __align__(16) float q2_lds[DA];
    __shared__ float red[4];
    const int b = blockIdx.x, d = threadIdx.x;
    float x = bq[d];
    #pragma unroll
    for (int ks = 0; ks < 8; ++ks) x += qp[ks * BD + b * DA + d];
    float mu = block_reduce_sum(x, red) * (1.0f / DA);
    float xc = x - mu;
    float var = block_reduce_sum(xc * xc, red) * (1.0f / DA);
    float qv = xc * rsqrtf(var + 1e-5f) * gq[d] + bqln[d];
    q_lds[d] = qv;
    __syncthreads();

    float q2 = 0.f;
    for (int f = 0; f < DA; f += 4) {
        float4 qf = *reinterpret_cast<const float4*>(&q_lds[f]);
        q2 = fmaf(qf.x, UqT[(f + 0) * DA + d], q2);
        q2 = fmaf(qf.y, UqT[(f + 1) * DA + d], q2);
        q2 = fmaf(qf.z, UqT[(f + 2) * DA + d], q2);
        q2 = fmaf(qf.w, UqT[(f + 3) * DA + d], q2);
    }
    q2_lds[d] = q2;
    __syncthreads();

    float r = 0.f;
    for (int e = 0; e < DA; e += 4) {
        float4 qe = *reinterpret_cast<const float4*>(&q2_lds[e]);
        r = fmaf(qe.x, Vk[(e + 0) * DA + d], r);
        r = fmaf(qe.y, Vk[(e + 1) * DA + d], r);
        r = fmaf(qe.z, Vk[(e + 2) * DA + d], r);
        r = fmaf(qe.w, Vk[(e + 3) * DA + d], r);
    }
    float grv = gk[d] * r;
    gr[b * DA + d] = grv;

    float Wg = block_reduce_sum(wk[d] * grv, red);
    float Cg = block_reduce_sum(bk[d] * grv, red);
    float G_ = block_reduce_sum(grv, red);
    float Bb = block_reduce_sum(bkln[d] * r, red);
    if (d == 0) {
        bscal[b] = Wg; bscal[B + b] = Cg;
        bscal[2 * B + b] = G_; bscal[3 * B + b] = Bb;
    }
}

// ---------------------------------------------------------------- KD: epart[ks] = gr @ Ek^T, KS=2 (chunk 128), R3 config
__global__ __launch_bounds__(256) void KD(const float* __restrict__ gr, const float* __restrict__ Ek,
                                          float* __restrict__ epart) {
    __shared__ __align__(16) float sA[32 * LDP];
    __shared__ __align__(16) float sB[32 * LDP];
    const int tid = threadIdx.x, t = blockIdx.x;
    const int ty4 = (tid >> 4) * 4, tx4 = (tid & 15) * 4;
    const int mt = t & 7, nt = (t >> 3) & 15, ks = t >> 7;
    const int b0 = mt * 64, p0 = nt * 64, kc = ks * 128;
    float acc[4][4] = {};
    for (int kt = 0; kt < 128; kt += 32) {
        stage_T(gr, DA, b0, kc + kt, tid, sA);
        stage_T(Ek, DA, p0, kc + kt, tid, sB);
        __syncthreads();
        mm_inner(sA, sB, tid, acc);
        __syncthreads();
    }
    float* outp = epart + ks * BP;
    #pragma unroll
    for (int i = 0; i < 4; ++i) {
        float4 o = make_float4(acc[i][0], acc[i][1], acc[i][2], acc[i][3]);
        *reinterpret_cast<float4*>(&outp[(b0 + ty4 + i) * P + p0 + tx4]) = o;
    }
}

// ---------------------------------------------------------------- KF: cpart[ks] = w @ Ev, KS=8 (chunk 128); w computed in A-staging
__global__ __launch_bounds__(256) void KF(const float* __restrict__ epart, const float* __restrict__ desc,
                                          const float* __restrict__ bscal, const float* __restrict__ pst,
                                          const float* __restrict__ scal4, const float* __restrict__ Ev,
                                          float* __restrict__ cpart) {
    __shared__ __align__(16) float sA[32 * LDP];
    __shared__ __align__(16) float sB[32 * LDP];
    const int tid = threadIdx.x, t = blockIdx.x;
    const int ty4 = (tid >> 4) * 4, tx4 = (tid & 15) * 4;
    const int mt = t & 7, nt = (t >> 3) & 3, ks = t >> 5;
    const int b0 = mt * 64, d0 = nt * 64, kc = ks * 128;
    const float mwk = scal4[0], Ak = scal4[1], Av = scal4[3];
    const int m = tid >> 3, k4 = (tid & 7) * 4;
    float acc[4][4] = {};
    for (int kt = 0; kt < 128; kt += 32) {
        const int kg = kc + kt;   // p-offset of this 32-slice
        // ---- A-stage: compute w[b][p] on the fly -> sA[p][b]
        #pragma unroll
        for (int pass = 0; pass < 2; ++pass) {
            int mm = m + pass * 32;
            const int b = b0 + mm;
            const int p = kg + k4;
            float4 e0 = *reinterpret_cast<const float4*>(&epart[b * P + p]);
            float4 e1 = *reinterpret_cast<const float4*>(&epart[BP + b * P + p]);
            float4 s4 = *reinterpret_cast<const float4*>(&desc[b * P + p]);
            float4 mck4 = *reinterpret_cast<const float4*>(&pst[p]);
            float4 Bk4  = *reinterpret_cast<const float4*>(&pst[P + p]);
            float4 Ck4  = *reinterpret_cast<const float4*>(&pst[2 * P + p]);
            float4 Bv4  = *reinterpret_cast<const float4*>(&pst[4 * P + p]);
            float4 Cv4  = *reinterpret_cast<const float4*>(&pst[5 * P + p]);
            const float Wg = bscal[b], Cg = bscal[B + b];
            const float G_ = bscal[2 * B + b], Bb = bscal[3 * B + b];
            float u, w;
            epilog_uw(e0.x + e1.x, s4.x, mck4.x, Bk4.x, Ck4.x, Bv4.x, Cv4.x,
                      mwk, Ak, Av, Wg, Cg, G_, Bb, u, w);
            sA[(k4 + 0) * LDP + mm] = w;
            epilog_uw(e0.y + e1.y, s4.y, mck4.y, Bk4.y, Ck4.y, Bv4.y, Cv4.y,
                      mwk, Ak, Av, Wg, Cg, G_, Bb, u, w);
            sA[(k4 + 1) * LDP + mm] = w;
            epilog_uw(e0.z + e1.z, s4.z, mck4.z, Bk4.z, Ck4.z, Bv4.z, Cv4.z,
                      mwk, Ak, Av, Wg, Cg, G_, Bb, u, w);
            sA[(k4 + 2) * LDP + mm] = w;
            epilog_uw(e0.w + e1.w, s4.w, mck4.w, Bk4.w, Ck4.w, Bv4.w, Cv4.w,
                      mwk, Ak, Av, Wg, Cg, G_, Bb, u, w);
            sA[(k4 + 3) * LDP + mm] = w;
        }
        stage_N1(Ev, DA, kg, d0, tid, sB);
        __syncthreads();
        mm_inner(sA, sB, tid, acc);
        __syncthreads();
    }
    float* outp = cpart + ks * BD;
    #pragma unroll
    for (int i = 0; i < 4; ++i) {
        float4 o = make_float4(acc[i][0], acc[i][1], acc[i][2], acc[i][3]);
        *reinterpret_cast<float4*>(&outp[(b0 + ty4 + i) * DA + d0 + tx4]) = o;
    }
}

// ---------------------------------------------------------------- KG: per-b full epilogue: u,w -> scalars -> alpha, final c
__global__ __launch_bounds__(256) void KG(const float* __restrict__ epart, const float* __restrict__ desc,
                                          const float* __restrict__ bscal, const float* __restrict__ pst,
                                          const float* __restrict__ scal4, const float* __restrict__ cpart,
                                          const float* __restrict__ gv, const float* __restrict__ wv,
                                          const float* __restrict__ bvv, const float* __restrict__ bvln,
                                          float* __restrict__ alpha_out, float* __restrict__ out_c) {
    __shared__ float red[4];
    const int b = blockIdx.x, tid = threadIdx.x;
    const float mwk = scal4[0], Ak = scal4[1], mwv = scal4[2], Av = scal4[3];
    const float Wg = bscal[b], Cg = bscal[B + b], G_ = bscal[2 * B + b], Bb = bscal[3 * B + b];
    float u[4];
    float us = 0.f, ws_ = 0.f, wss = 0.f, wms = 0.f;
    #pragma unroll
    for (int j = 0; j < 4; ++j) {
        int p = j * 256 + tid;
        float dot = epart[b * P + p] + epart[BP + b * P + p];
        float s = desc[b * P + p];
        float uu, ww;
        epilog_uw(dot, s, pst[p], pst[P + p], pst[2 * P + p], pst[4 * P + p], pst[5 * P + p],
                  mwk, Ak, Av, Wg, Cg, G_, Bb, uu, ww);
        u[j] = uu;
        us += uu; ws_ += ww;
        wss = fmaf(ww, s, wss);
        wms = fmaf(ww, fmaf(s, mwv, pst[3 * P + p]), wms);
    }
    float S   = block_reduce_sum(us, red);
    float SB  = block_reduce_sum(ws_, red);
    float SBs = block_reduce_sum(wss, red);
    float SBm = block_reduce_sum(wms, red);
    float invS = 1.0f / (S + 1e-12f);
    float T = S * invS;
    #pragma unroll
    for (int j = 0; j < 4; ++j)
        alpha_out[b * P + j * 256 + tid] = u[j] * invS;
    const int d = tid;
    float csum = 0.f;
    #pragma unroll
    for (int ks = 0; ks < 8; ++ks) csum += cpart[ks * BD + b * DA + d];
    out_c[b * DA + d] =
        invS * (gv[d] * (wv[d] * SBs + bvv[d] * SB + csum - SBm)) + bvln[d] * T;
}

// ---------------------------------------------------------------- launch
extern "C" void kernel_launch(void* const* d_in, const int* in_sizes, int n_in,
                              void* d_out, int out_size, void* d_ws, size_t ws_size,
                              hipStream_t stream) {
    (void)in_sizes; (void)n_in; (void)out_size; (void)ws_size;
    const float* hg   = (const float*)d_in[0];
    const float* desc = (const float*)d_in[1];
    const float* Wq   = (const float*)d_in[2];
    const float* bq   = (const float*)d_in[3];
    const float* wk   = (const float*)d_in[4];
    const float* bk   = (const float*)d_in[5];
    const float* wv   = (const float*)d_in[6];
    const float* bv   = (const float*)d_in[7];
    const float* Ek   = (const float*)d_in[8];
    const float* Ev   = (const float*)d_in[9];
    const float* Uq   = (const float*)d_in[10];
    const float* Vk   = (const float*)d_in[11];
    const float* gq   = (const float*)d_in[12];
    const float* bqln = (const float*)d_in[13];
    const float* gk   = (const float*)d_in[14];
    const float* bkln = (const float*)d_in[15];
    const float* gv   = (const float*)d_in[16];
    const float* bvln = (const float*)d_in[17];

    float* out = (float*)d_out;
    float* out_c = out;              // B*DA
    float* out_alpha = out + BD;     // B*P

    float* ws = (float*)d_ws;
    float* qp    = ws;               // 8 * BD   = 1048576
    float* UqT   = ws + 1048576;     // 65536
    float* gr    = ws + 1114112;     // 131072
    float* epart = ws + 1245184;     // 2 * BP   = 1048576
    float* cpart = ws + 2293760;     // 8 * BD   = 1048576
    float* bscal = ws + 3342336;     // 2048
    float* pst   = ws + 3344384;     // 6144
    float* scal4 = ws + 3350528;     // 4

    KA<<<576, 256, 0, stream>>>(hg, Wq, Uq, Ek, Ev, wk, bk, wv, bv, qp, UqT, pst, scal4);
    KC<<<512, 256, 0, stream>>>(qp, bq, gq, bqln, UqT, Vk, gk, wk, bk, bkln, gr, bscal);
    KD<<<256, 256, 0, stream>>>(gr, Ek, epart);
    KF<<<256, 256, 0, stream>>>(epart, desc, bscal, pst, scal4, Ev, cpart);
    KG<<<512, 256, 0, stream>>>(epart, desc, bscal, pst, scal4, cpart, gv, wv, bv, bvln,
                                out_alpha, out_c);
}